// Round 1
// baseline (13684.732 us; speedup 1.0000x reference)
//
#include <hip/hip_runtime.h>

// ODE_Vanilla scan: B=128, T=256, I=256, H=1024, C=10, fp32 throughout.
// Per step t:
//   phase1: v = a*h - relu(h@Wh + XW[t] )   (XW = X@Wx + b precomputed)
//   phase2: u = v@Wh^T; grad = a*v - (phi>0)*u; h -= LR*grad
// R3: XCD-affine column ownership (each XCD owns 128 cols of Wh AND WhT ->
// weight slices stay L2-resident, ~8x less L3->L2 traffic), X@Wx+b hoisted
// out of the scan into one GEMM (ws-size-guarded fallback), FC epilogue
// folded into next step's phase1 (no atomics, no out-init).

constexpr int Bsz = 128, Tn = 256, In = 256, Hn = 1024, Cn = 10;
constexpr float LR = 0.001f;
constexpr int HP = 1024 + 32;  // 8 chunks of 128, each padded +4 floats
#define HSW(k) ((k) + (((k) >> 7) << 2))  // swizzled LDS index

__global__ __launch_bounds__(256) void k_transpose(const float* __restrict__ W,
                                                   float* __restrict__ WT) {
  __shared__ float tile[32][33];
  const int bx = blockIdx.x * 32, by = blockIdx.y * 32;
  const int tx = threadIdx.x & 31, ty = threadIdx.x >> 5;
#pragma unroll
  for (int dy = 0; dy < 32; dy += 8)
    tile[ty + dy][tx] = W[(size_t)(by + ty + dy) * Hn + bx + tx];
  __syncthreads();
#pragma unroll
  for (int dy = 0; dy < 32; dy += 8)
    WT[(size_t)(bx + ty + dy) * Hn + by + tx] = tile[tx][ty + dy];
}

__global__ __launch_bounds__(256) void k_init(float* __restrict__ h_cur,
                                              const float* __restrict__ hidden) {
  const int i = blockIdx.x * 256 + threadIdx.x;  // grid 512 covers 128*1024
  h_cur[i] = hidden[i];
}

__device__ __forceinline__ void fma4(float4& a, float s, const float4& w) {
  a.x = fmaf(s, w.x, a.x);
  a.y = fmaf(s, w.y, a.y);
  a.z = fmaf(s, w.z, a.z);
  a.w = fmaf(s, w.w, a.w);
}

__device__ __forceinline__ void red_ks(float4& a) {
#pragma unroll
  for (int m = 4; m <= 16; m <<= 1) {  // ks lives in lane bits 2..4
    a.x += __shfl_xor(a.x, m, 64);
    a.y += __shfl_xor(a.y, m, 64);
    a.z += __shfl_xor(a.z, m, 64);
    a.w += __shfl_xor(a.w, m, 64);
  }
}

// XW[t][b][n] = sum_k X[b][t][k]*Wx[k][n] + bias[n].
// grid 8192 = mt(512: t*2 + bhalf) x nt(16); thread = cl(16 cols of 4) x rg(16 rows of 4)
__global__ __launch_bounds__(256) void k_xw(const float* __restrict__ X,
                                            const float* __restrict__ Wx,
                                            const float* __restrict__ bias,
                                            float* __restrict__ xw) {
  const int nt = blockIdx.x & 15, mt = blockIdx.x >> 4;
  const int t = mt >> 1, b0 = (mt & 1) * 64;
  const int cl = threadIdx.x & 15, rg = threadIdx.x >> 4;
  const int col = nt * 64 + cl * 4;
  const int row = b0 + rg * 4;
  float4 acc0 = {0, 0, 0, 0}, acc1 = {0, 0, 0, 0}, acc2 = {0, 0, 0, 0},
         acc3 = {0, 0, 0, 0};
  const size_t xstride = (size_t)Tn * In;
  const float* xp = X + ((size_t)row * Tn + t) * In;
  const float* wp = Wx + col;
#pragma unroll 2
  for (int k = 0; k < In; k += 4) {
    const float4 x0 = *(const float4*)(xp + k);
    const float4 x1 = *(const float4*)(xp + xstride + k);
    const float4 x2 = *(const float4*)(xp + 2 * xstride + k);
    const float4 x3 = *(const float4*)(xp + 3 * xstride + k);
    const float4 w0 = *(const float4*)(wp + (size_t)k * Hn);
    const float4 w1 = *(const float4*)(wp + (size_t)(k + 1) * Hn);
    const float4 w2 = *(const float4*)(wp + (size_t)(k + 2) * Hn);
    const float4 w3 = *(const float4*)(wp + (size_t)(k + 3) * Hn);
    fma4(acc0, x0.x, w0); fma4(acc0, x0.y, w1); fma4(acc0, x0.z, w2); fma4(acc0, x0.w, w3);
    fma4(acc1, x1.x, w0); fma4(acc1, x1.y, w1); fma4(acc1, x1.z, w2); fma4(acc1, x1.w, w3);
    fma4(acc2, x2.x, w0); fma4(acc2, x2.y, w1); fma4(acc2, x2.z, w2); fma4(acc2, x2.w, w3);
    fma4(acc3, x3.x, w0); fma4(acc3, x3.y, w1); fma4(acc3, x3.z, w2); fma4(acc3, x3.w, w3);
  }
  const float4 b4 = *(const float4*)(bias + col);
  float4 o[4] = {acc0, acc1, acc2, acc3};
#pragma unroll
  for (int i = 0; i < 4; i++) {
    float4 v = o[i];
    v.x += b4.x; v.y += b4.y; v.z += b4.z; v.w += b4.w;
    *(float4*)(xw + ((size_t)t * Bsz + row + i) * Hn + col) = v;
  }
}

// grid 1024; XCD-affine swizzle: xcd = bid&7 owns cols [xcd*128, xcd*128+128)
// thread = c4(4) x ks(8) x r(8)
template <int PRE>
__global__ __launch_bounds__(256, 4) void k_phase1(
    const float* __restrict__ h, const float* __restrict__ X,
    const float* __restrict__ Wh, const float* __restrict__ Wx,
    const float* __restrict__ bias, const float* __restrict__ alpha,
    const float* __restrict__ xw, const float* __restrict__ fc_w,
    const float* __restrict__ fc_b, float* __restrict__ out,
    float* __restrict__ v_out, int t) {
  __shared__ float h_s[8][HP];
  const int ct = (blockIdx.x & 7) * 8 + ((blockIdx.x >> 3) & 7);
  const int rt = blockIdx.x >> 6;
  const int c0 = ct * 16, r0 = rt * 8;
  const int tid = threadIdx.x;
  {  // stage 8 h rows (8192 contiguous floats), swizzled LDS layout
    const float4* src = (const float4*)(h + (size_t)r0 * Hn);
#pragma unroll
    for (int u = 0; u < 8; u++) {
      const int f = tid + 256 * u;
      const int row = f >> 8, k = (f & 255) * 4;
      *(float4*)&h_s[row][HSW(k)] = src[f];
    }
  }
  __syncthreads();

  const int c4 = tid & 3, ks = (tid >> 2) & 7, r = tid >> 5;
  const int col = c0 + 4 * c4;
  float4 aA = {0, 0, 0, 0}, aB = {0, 0, 0, 0};
  {  // Wh part: K-chunk [ks*128, ks*128+128)
    const float* hr = &h_s[r][ks * 132];
    const float* Wp = Wh + (size_t)(ks * 128) * Hn + col;
#pragma unroll 2
    for (int q = 0; q < 32; q++) {
      const float4 h4 = *(const float4*)(hr + 4 * q);
      const float4 w0 = *(const float4*)(Wp);
      const float4 w1 = *(const float4*)(Wp + Hn);
      const float4 w2 = *(const float4*)(Wp + 2 * Hn);
      const float4 w3 = *(const float4*)(Wp + 3 * Hn);
      Wp += 4 * Hn;
      fma4(aA, h4.x, w0);
      fma4(aA, h4.y, w1);
      fma4(aB, h4.z, w2);
      fma4(aB, h4.w, w3);
    }
  }
  if (!PRE) {  // Wx part: I-chunk [ks*32, ks*32+32), x straight from global
    const float* xp = X + ((size_t)(r0 + r) * Tn + t) * In + ks * 32;
    const float* Wp = Wx + (size_t)(ks * 32) * Hn + col;
#pragma unroll 2
    for (int q = 0; q < 8; q++) {
      const float4 x4 = *(const float4*)(xp + 4 * q);
      const float4 w0 = *(const float4*)(Wp);
      const float4 w1 = *(const float4*)(Wp + Hn);
      const float4 w2 = *(const float4*)(Wp + 2 * Hn);
      const float4 w3 = *(const float4*)(Wp + 3 * Hn);
      Wp += 4 * Hn;
      fma4(aA, x4.x, w0);
      fma4(aA, x4.y, w1);
      fma4(aB, x4.z, w2);
      fma4(aB, x4.w, w3);
    }
  }
  float4 acc = {aA.x + aB.x, aA.y + aB.y, aA.z + aB.z, aA.w + aB.w};
  red_ks(acc);
  if (ks == 0) {
    float4 a4;
    if (PRE)
      a4 = *(const float4*)(xw + ((size_t)t * Bsz + r0 + r) * Hn + col);
    else
      a4 = *(const float4*)(bias + col);
    const float av = alpha[0];
    const float4 hv = *(const float4*)(&h_s[r][HSW(col)]);
    float4 v;
    v.x = av * hv.x - fmaxf(acc.x + a4.x, 0.f);
    v.y = av * hv.y - fmaxf(acc.y + a4.y, 0.f);
    v.z = av * hv.z - fmaxf(acc.z + a4.z, 0.f);
    v.w = av * hv.w - fmaxf(acc.w + a4.w, 0.f);
    *(float4*)(v_out + (size_t)(r0 + r) * Hn + col) = v;
  }
  // FC fold: h_s holds h after step t-1 -> out[:, t-1, :]. Only ct==0 blocks.
  if (ct == 0 && t > 0) {
    const int r2 = tid >> 5, l = tid & 31, c = l & 15, half = l >> 4;
    float s = 0.f;
    if (c < Cn) {
      const int kbase = half * 512;
#pragma unroll 4
      for (int kk = 0; kk < 512; kk += 4) {
        const float4 h4 = *(const float4*)(&h_s[r2][HSW(kbase + kk)]);
        const float* fw = fc_w + (size_t)(kbase + kk) * Cn + c;
        s = fmaf(h4.x, fw[0], s);
        s = fmaf(h4.y, fw[Cn], s);
        s = fmaf(h4.z, fw[2 * Cn], s);
        s = fmaf(h4.w, fw[3 * Cn], s);
      }
    }
    s += __shfl_xor(s, 16, 64);
    if (c < Cn && half == 0)
      out[((size_t)(r0 + r2) * Tn + (t - 1)) * Cn + c] = s + fc_b[c];
  }
}

__global__ __launch_bounds__(256, 4) void k_phase2(
    float* __restrict__ h, const float* __restrict__ v_in,
    const float* __restrict__ WT, const float* __restrict__ alpha,
    float* __restrict__ hfin, int last) {
  __shared__ float v_s[8][HP];
  const int ct = (blockIdx.x & 7) * 8 + ((blockIdx.x >> 3) & 7);
  const int rt = blockIdx.x >> 6;
  const int c0 = ct * 16, r0 = rt * 8;
  const int tid = threadIdx.x;
  {
    const float4* src = (const float4*)(v_in + (size_t)r0 * Hn);
#pragma unroll
    for (int u = 0; u < 8; u++) {
      const int f = tid + 256 * u;
      const int row = f >> 8, k = (f & 255) * 4;
      *(float4*)&v_s[row][HSW(k)] = src[f];
    }
  }
  __syncthreads();

  const int c4 = tid & 3, ks = (tid >> 2) & 7, r = tid >> 5;
  const int col = c0 + 4 * c4;
  float4 aA = {0, 0, 0, 0}, aB = {0, 0, 0, 0};
  {
    const float* vr = &v_s[r][ks * 132];
    const float* Wp = WT + (size_t)(ks * 128) * Hn + col;
#pragma unroll 2
    for (int q = 0; q < 32; q++) {
      const float4 v4 = *(const float4*)(vr + 4 * q);
      const float4 w0 = *(const float4*)(Wp);
      const float4 w1 = *(const float4*)(Wp + Hn);
      const float4 w2 = *(const float4*)(Wp + 2 * Hn);
      const float4 w3 = *(const float4*)(Wp + 3 * Hn);
      Wp += 4 * Hn;
      fma4(aA, v4.x, w0);
      fma4(aA, v4.y, w1);
      fma4(aB, v4.z, w2);
      fma4(aB, v4.w, w3);
    }
  }
  float4 acc = {aA.x + aB.x, aA.y + aB.y, aA.z + aB.z, aA.w + aB.w};
  red_ks(acc);
  if (ks == 0) {
    const float av = alpha[0];
    const float4 vv = *(const float4*)(&v_s[r][HSW(col)]);
    const size_t hoff = (size_t)(r0 + r) * Hn + col;
    const float4 hv = *(const float4*)(h + hoff);
    float4 hn;  // phi = a*h - v; grad = a*v - (phi>0)*u; hn = h - LR*grad
    hn.x = hv.x - LR * (av * vv.x - ((av * hv.x - vv.x) > 0.f ? acc.x : 0.f));
    hn.y = hv.y - LR * (av * vv.y - ((av * hv.y - vv.y) > 0.f ? acc.y : 0.f));
    hn.z = hv.z - LR * (av * vv.z - ((av * hv.z - vv.z) > 0.f ? acc.z : 0.f));
    hn.w = hv.w - LR * (av * vv.w - ((av * hv.w - vv.w) > 0.f ? acc.w : 0.f));
    *(float4*)(h + hoff) = hn;
    if (last) *(float4*)(hfin + hoff) = hn;
  }
}

// FC for the final timestep: out[:, T-1, :] = h_final @ fc_w + fc_b. grid 16.
__global__ __launch_bounds__(256) void k_fc_last(const float* __restrict__ h,
                                                 const float* __restrict__ fc_w,
                                                 const float* __restrict__ fc_b,
                                                 float* __restrict__ out) {
  const int r0 = blockIdx.x * 8;
  const int r = threadIdx.x >> 5, l = threadIdx.x & 31;
  const int c = l & 15, half = l >> 4;
  float s = 0.f;
  if (c < Cn) {
    const float* hp = h + (size_t)(r0 + r) * Hn + half * 512;
#pragma unroll 4
    for (int k = 0; k < 512; k += 4) {
      const float4 h4 = *(const float4*)(hp + k);
      const float* fw = fc_w + (size_t)(half * 512 + k) * Cn + c;
      s = fmaf(h4.x, fw[0], s);
      s = fmaf(h4.y, fw[Cn], s);
      s = fmaf(h4.z, fw[2 * Cn], s);
      s = fmaf(h4.w, fw[3 * Cn], s);
    }
  }
  s += __shfl_xor(s, 16, 64);
  if (c < Cn && half == 0)
    out[((size_t)(r0 + r) * Tn + (Tn - 1)) * Cn + c] = s + fc_b[c];
}

extern "C" void kernel_launch(void* const* d_in, const int* in_sizes, int n_in,
                              void* d_out, int out_size, void* d_ws, size_t ws_size,
                              hipStream_t stream) {
  const float* X      = (const float*)d_in[0];
  const float* hidden = (const float*)d_in[1];
  const float* alpha  = (const float*)d_in[2];
  const float* bias   = (const float*)d_in[3];
  const float* Wh     = (const float*)d_in[4];
  const float* Wx     = (const float*)d_in[5];
  const float* fc_w   = (const float*)d_in[6];
  const float* fc_b   = (const float*)d_in[7];
  float* out  = (float*)d_out;
  float* hfin = out + (size_t)Bsz * Tn * Cn;

  char* ws = (char*)d_ws;
  float* WhT   = (float*)ws;  // 4 MB
  float* h_cur = (float*)(ws + (size_t)Hn * Hn * sizeof(float));
  float* v_buf = h_cur + (size_t)Bsz * Hn;
  float* XW    = v_buf + (size_t)Bsz * Hn;  // 134 MB, [t][b][n]
  const size_t need =
      ((size_t)Hn * Hn + 2 * (size_t)Bsz * Hn + (size_t)Bsz * Tn * Hn) *
      sizeof(float);
  const bool pre = ws_size >= need;

  k_transpose<<<dim3(32, 32), 256, 0, stream>>>(Wh, WhT);
  k_init<<<512, 256, 0, stream>>>(h_cur, hidden);
  if (pre) k_xw<<<8192, 256, 0, stream>>>(X, Wx, bias, XW);
  for (int t = 0; t < Tn; t++) {
    if (pre)
      k_phase1<1><<<1024, 256, 0, stream>>>(h_cur, X, Wh, Wx, bias, alpha, XW,
                                            fc_w, fc_b, out, v_buf, t);
    else
      k_phase1<0><<<1024, 256, 0, stream>>>(h_cur, X, Wh, Wx, bias, alpha, XW,
                                            fc_w, fc_b, out, v_buf, t);
    k_phase2<<<1024, 256, 0, stream>>>(h_cur, v_buf, WhT, alpha, hfin,
                                       t == Tn - 1);
  }
  k_fc_last<<<16, 256, 0, stream>>>(h_cur, fc_w, fc_b, out);
}

// Round 2
// 7381.562 us; speedup vs baseline: 1.8539x; 1.8539x over previous
//
#include <hip/hip_runtime.h>

// ODE_Vanilla scan: B=128, T=256, I=256, H=1024, C=10, fp32 throughout.
// Per step t:
//   phase1: v = a*h - relu(h@Wh + XW[t])   (XW = X@Wx + b precomputed)
//   phase2: u = v@Wh^T; grad = a*v - (phi>0)*u; h -= LR*grad; out[b,t,:] = h@fc_w+fc_b
// R4: register row-tiling in the phase GEMMs — each thread loads a W float4
// once and FMAs it against all 8 batch rows (64-way K-split, kk = tid>>2),
// cutting per-block W traffic from 512 KB to the 64 KB unique minimum
// (~8x less L2 traffic; phases were L2-BW-bound). In-wave butterfly reduce
// (lane bits 2..5) + 4-way cross-wave LDS combine. FC epilogue reverted to
// R2's distributed atomic form; XCD swizzle reverted (was a no-op).

constexpr int Bsz = 128, Tn = 256, In = 256, Hn = 1024, Cn = 10;
constexpr float LR = 0.001f;
constexpr int HP = 1024 + 32;  // 8 chunks of 128, each padded +4 floats
#define HSW(k) ((k) + (((k) >> 7) << 2))  // swizzled LDS index

__global__ __launch_bounds__(256) void k_transpose(const float* __restrict__ W,
                                                   float* __restrict__ WT) {
  __shared__ float tile[32][33];
  const int bx = blockIdx.x * 32, by = blockIdx.y * 32;
  const int tx = threadIdx.x & 31, ty = threadIdx.x >> 5;
#pragma unroll
  for (int dy = 0; dy < 32; dy += 8)
    tile[ty + dy][tx] = W[(size_t)(by + ty + dy) * Hn + bx + tx];
  __syncthreads();
#pragma unroll
  for (int dy = 0; dy < 32; dy += 8)
    WT[(size_t)(bx + ty + dy) * Hn + by + tx] = tile[tx][ty + dy];
}

__global__ __launch_bounds__(256) void k_init(float* __restrict__ out,
                                              const float* __restrict__ fc_b,
                                              float* __restrict__ h_cur,
                                              const float* __restrict__ hidden) {
  const int i = blockIdx.x * blockDim.x + threadIdx.x;
  if (i < Bsz * Tn * Cn) out[i] = fc_b[i % Cn];
  if (i < Bsz * Hn) h_cur[i] = hidden[i];
}

__device__ __forceinline__ void fma4(float4& a, float s, const float4& w) {
  a.x = fmaf(s, w.x, a.x);
  a.y = fmaf(s, w.y, a.y);
  a.z = fmaf(s, w.z, a.z);
  a.w = fmaf(s, w.w, a.w);
}

__device__ __forceinline__ void red4(float4& a, int m) {
  a.x += __shfl_xor(a.x, m, 64);
  a.y += __shfl_xor(a.y, m, 64);
  a.z += __shfl_xor(a.z, m, 64);
  a.w += __shfl_xor(a.w, m, 64);
}

// XW[t][b][n] = sum_k X[b][t][k]*Wx[k][n] + bias[n].
__global__ __launch_bounds__(256) void k_xw(const float* __restrict__ X,
                                            const float* __restrict__ Wx,
                                            const float* __restrict__ bias,
                                            float* __restrict__ xw) {
  const int nt = blockIdx.x & 15, mt = blockIdx.x >> 4;
  const int t = mt >> 1, b0 = (mt & 1) * 64;
  const int cl = threadIdx.x & 15, rg = threadIdx.x >> 4;
  const int col = nt * 64 + cl * 4;
  const int row = b0 + rg * 4;
  float4 acc0 = {0, 0, 0, 0}, acc1 = {0, 0, 0, 0}, acc2 = {0, 0, 0, 0},
         acc3 = {0, 0, 0, 0};
  const size_t xstride = (size_t)Tn * In;
  const float* xp = X + ((size_t)row * Tn + t) * In;
  const float* wp = Wx + col;
#pragma unroll 2
  for (int k = 0; k < In; k += 4) {
    const float4 x0 = *(const float4*)(xp + k);
    const float4 x1 = *(const float4*)(xp + xstride + k);
    const float4 x2 = *(const float4*)(xp + 2 * xstride + k);
    const float4 x3 = *(const float4*)(xp + 3 * xstride + k);
    const float4 w0 = *(const float4*)(wp + (size_t)k * Hn);
    const float4 w1 = *(const float4*)(wp + (size_t)(k + 1) * Hn);
    const float4 w2 = *(const float4*)(wp + (size_t)(k + 2) * Hn);
    const float4 w3 = *(const float4*)(wp + (size_t)(k + 3) * Hn);
    fma4(acc0, x0.x, w0); fma4(acc0, x0.y, w1); fma4(acc0, x0.z, w2); fma4(acc0, x0.w, w3);
    fma4(acc1, x1.x, w0); fma4(acc1, x1.y, w1); fma4(acc1, x1.z, w2); fma4(acc1, x1.w, w3);
    fma4(acc2, x2.x, w0); fma4(acc2, x2.y, w1); fma4(acc2, x2.z, w2); fma4(acc2, x2.w, w3);
    fma4(acc3, x3.x, w0); fma4(acc3, x3.y, w1); fma4(acc3, x3.z, w2); fma4(acc3, x3.w, w3);
  }
  const float4 b4 = *(const float4*)(bias + col);
  float4 o[4] = {acc0, acc1, acc2, acc3};
#pragma unroll
  for (int i = 0; i < 4; i++) {
    float4 v = o[i];
    v.x += b4.x; v.y += b4.y; v.z += b4.z; v.w += b4.w;
    *(float4*)(xw + ((size_t)t * Bsz + row + i) * Hn + col) = v;
  }
}

// grid 1024 = rt(16, 8 rows) x ct(64, 16 cols); thread = c4(4) x kk(64).
// Thread kk owns K-quads {kk + 64q, q=0..3} (k = 4kk + 256q); each W float4
// is loaded once and FMA'd against all 8 rows from LDS (b128, 2-way banks).
template <int PRE>
__global__ __launch_bounds__(256, 4) void k_phase1(
    const float* __restrict__ h, const float* __restrict__ X,
    const float* __restrict__ Wh, const float* __restrict__ Wx,
    const float* __restrict__ bias, const float* __restrict__ alpha,
    const float* __restrict__ xw, float* __restrict__ v_out, int t) {
  __shared__ float h_s[8][HP];
  __shared__ float4 part[4][4][8];
  const int ct = blockIdx.x & 63, rt = blockIdx.x >> 6;
  const int c0 = ct * 16, r0 = rt * 8;
  const int tid = threadIdx.x;
  {  // stage 8 h rows (8192 contiguous floats), swizzled LDS layout
    const float4* src = (const float4*)(h + (size_t)r0 * Hn);
#pragma unroll
    for (int u = 0; u < 8; u++) {
      const int f = tid + 256 * u;
      const int row = f >> 8, k = (f & 255) * 4;
      *(float4*)&h_s[row][HSW(k)] = src[f];
    }
  }
  __syncthreads();

  const int c4 = tid & 3, kk = tid >> 2;
  const int col = c0 + 4 * c4;
  float4 acc[8];
#pragma unroll
  for (int r = 0; r < 8; r++) acc[r] = {0.f, 0.f, 0.f, 0.f};

#pragma unroll
  for (int q = 0; q < 4; q++) {
    const int k = 4 * kk + 256 * q;
    const float* Wp = Wh + (size_t)k * Hn + col;
    const float4 w0 = *(const float4*)(Wp);
    const float4 w1 = *(const float4*)(Wp + Hn);
    const float4 w2 = *(const float4*)(Wp + 2 * Hn);
    const float4 w3 = *(const float4*)(Wp + 3 * Hn);
#pragma unroll
    for (int r = 0; r < 8; r++) {
      const float4 h4 = *(const float4*)(&h_s[r][HSW(k)]);
      fma4(acc[r], h4.x, w0);
      fma4(acc[r], h4.y, w1);
      fma4(acc[r], h4.z, w2);
      fma4(acc[r], h4.w, w3);
    }
  }
  if (!PRE) {  // x@Wx inline: thread kk owns Wx row-quad 4kk (I=256 = 64*4)
    const int kx = 4 * kk;
    const float* Wp = Wx + (size_t)kx * Hn + col;
    const float4 w0 = *(const float4*)(Wp);
    const float4 w1 = *(const float4*)(Wp + Hn);
    const float4 w2 = *(const float4*)(Wp + 2 * Hn);
    const float4 w3 = *(const float4*)(Wp + 3 * Hn);
#pragma unroll
    for (int r = 0; r < 8; r++) {
      const float4 x4 =
          *(const float4*)(X + ((size_t)(r0 + r) * Tn + t) * In + kx);
      fma4(acc[r], x4.x, w0);
      fma4(acc[r], x4.y, w1);
      fma4(acc[r], x4.z, w2);
      fma4(acc[r], x4.w, w3);
    }
  }
  // in-wave butterfly over kk low bits (lane bits 2..5)
#pragma unroll
  for (int m = 4; m <= 32; m <<= 1)
#pragma unroll
    for (int r = 0; r < 8; r++) red4(acc[r], m);
  const int wv = tid >> 6, lid = tid & 63;
  if (lid < 4) {  // lid == c4 here
#pragma unroll
    for (int r = 0; r < 8; r++) part[wv][lid][r] = acc[r];
  }
  __syncthreads();
  if (tid < 32) {  // cross-wave combine + epilogue
    const int r = tid >> 2, cc = tid & 3;
    float4 u = part[0][cc][r];
    const float4 p1 = part[1][cc][r], p2 = part[2][cc][r], p3 = part[3][cc][r];
    u.x += p1.x + p2.x + p3.x;
    u.y += p1.y + p2.y + p3.y;
    u.z += p1.z + p2.z + p3.z;
    u.w += p1.w + p2.w + p3.w;
    const int colo = c0 + 4 * cc;
    float4 a4;
    if (PRE)
      a4 = *(const float4*)(xw + ((size_t)t * Bsz + r0 + r) * Hn + colo);
    else
      a4 = *(const float4*)(bias + colo);
    const float av = alpha[0];
    const float4 hv = *(const float4*)(&h_s[r][HSW(colo)]);
    float4 v;
    v.x = av * hv.x - fmaxf(u.x + a4.x, 0.f);
    v.y = av * hv.y - fmaxf(u.y + a4.y, 0.f);
    v.z = av * hv.z - fmaxf(u.z + a4.z, 0.f);
    v.w = av * hv.w - fmaxf(u.w + a4.w, 0.f);
    *(float4*)(v_out + (size_t)(r0 + r) * Hn + colo) = v;
  }
}

__global__ __launch_bounds__(256, 4) void k_phase2(
    float* __restrict__ h, const float* __restrict__ v_in,
    const float* __restrict__ WT, const float* __restrict__ alpha,
    const float* __restrict__ fc_w, float* __restrict__ out,
    float* __restrict__ hfin, int t, int last) {
  __shared__ float v_s[8][HP];
  __shared__ float4 part[4][4][8];
  __shared__ float hn_s[8][16];
  const int ct = blockIdx.x & 63, rt = blockIdx.x >> 6;
  const int c0 = ct * 16, r0 = rt * 8;
  const int tid = threadIdx.x;
  {
    const float4* src = (const float4*)(v_in + (size_t)r0 * Hn);
#pragma unroll
    for (int u = 0; u < 8; u++) {
      const int f = tid + 256 * u;
      const int row = f >> 8, k = (f & 255) * 4;
      *(float4*)&v_s[row][HSW(k)] = src[f];
    }
  }
  __syncthreads();

  const int c4 = tid & 3, kk = tid >> 2;
  const int col = c0 + 4 * c4;
  float4 acc[8];
#pragma unroll
  for (int r = 0; r < 8; r++) acc[r] = {0.f, 0.f, 0.f, 0.f};

#pragma unroll
  for (int q = 0; q < 4; q++) {
    const int k = 4 * kk + 256 * q;
    const float* Wp = WT + (size_t)k * Hn + col;
    const float4 w0 = *(const float4*)(Wp);
    const float4 w1 = *(const float4*)(Wp + Hn);
    const float4 w2 = *(const float4*)(Wp + 2 * Hn);
    const float4 w3 = *(const float4*)(Wp + 3 * Hn);
#pragma unroll
    for (int r = 0; r < 8; r++) {
      const float4 v4 = *(const float4*)(&v_s[r][HSW(k)]);
      fma4(acc[r], v4.x, w0);
      fma4(acc[r], v4.y, w1);
      fma4(acc[r], v4.z, w2);
      fma4(acc[r], v4.w, w3);
    }
  }
#pragma unroll
  for (int m = 4; m <= 32; m <<= 1)
#pragma unroll
    for (int r = 0; r < 8; r++) red4(acc[r], m);
  const int wv = tid >> 6, lid = tid & 63;
  if (lid < 4) {
#pragma unroll
    for (int r = 0; r < 8; r++) part[wv][lid][r] = acc[r];
  }
  __syncthreads();
  if (tid < 32) {
    const int r = tid >> 2, cc = tid & 3;
    float4 u = part[0][cc][r];
    const float4 p1 = part[1][cc][r], p2 = part[2][cc][r], p3 = part[3][cc][r];
    u.x += p1.x + p2.x + p3.x;
    u.y += p1.y + p2.y + p3.y;
    u.z += p1.z + p2.z + p3.z;
    u.w += p1.w + p2.w + p3.w;
    const int colo = c0 + 4 * cc;
    const float av = alpha[0];
    const float4 vv = *(const float4*)(&v_s[r][HSW(colo)]);
    const size_t hoff = (size_t)(r0 + r) * Hn + colo;
    const float4 hv = *(const float4*)(h + hoff);
    float4 hn;  // phi = a*h - v; grad = a*v - (phi>0)*u; hn = h - LR*grad
    hn.x = hv.x - LR * (av * vv.x - ((av * hv.x - vv.x) > 0.f ? u.x : 0.f));
    hn.y = hv.y - LR * (av * vv.y - ((av * hv.y - vv.y) > 0.f ? u.y : 0.f));
    hn.z = hv.z - LR * (av * vv.z - ((av * hv.z - vv.z) > 0.f ? u.z : 0.f));
    hn.w = hv.w - LR * (av * vv.w - ((av * hv.w - vv.w) > 0.f ? u.w : 0.f));
    *(float4*)(h + hoff) = hn;
    if (last) *(float4*)(hfin + hoff) = hn;
    *(float4*)&hn_s[r][4 * cc] = hn;
  }
  __syncthreads();
  if (tid < 80) {  // FC partial over this block's 16 cols -> 80 atomics
    const int rr = tid / 10, c = tid % 10;
    float s = 0.f;
#pragma unroll
    for (int jj = 0; jj < 16; jj++)
      s += hn_s[rr][jj] * fc_w[(size_t)(c0 + jj) * Cn + c];
    atomicAdd(&out[((size_t)(r0 + rr) * Tn + t) * Cn + c], s);
  }
}

extern "C" void kernel_launch(void* const* d_in, const int* in_sizes, int n_in,
                              void* d_out, int out_size, void* d_ws, size_t ws_size,
                              hipStream_t stream) {
  const float* X      = (const float*)d_in[0];
  const float* hidden = (const float*)d_in[1];
  const float* alpha  = (const float*)d_in[2];
  const float* bias   = (const float*)d_in[3];
  const float* Wh     = (const float*)d_in[4];
  const float* Wx     = (const float*)d_in[5];
  const float* fc_w   = (const float*)d_in[6];
  const float* fc_b   = (const float*)d_in[7];
  float* out  = (float*)d_out;
  float* hfin = out + (size_t)Bsz * Tn * Cn;

  char* ws = (char*)d_ws;
  float* WhT   = (float*)ws;  // 4 MB
  float* h_cur = (float*)(ws + (size_t)Hn * Hn * sizeof(float));
  float* v_buf = h_cur + (size_t)Bsz * Hn;
  float* XW    = v_buf + (size_t)Bsz * Hn;  // 134 MB, [t][b][n]
  const size_t need =
      ((size_t)Hn * Hn + 2 * (size_t)Bsz * Hn + (size_t)Bsz * Tn * Hn) *
      sizeof(float);
  const bool pre = ws_size >= need;

  k_transpose<<<dim3(32, 32), 256, 0, stream>>>(Wh, WhT);
  k_init<<<(Bsz * Tn * Cn + 255) / 256, 256, 0, stream>>>(out, fc_b, h_cur, hidden);
  if (pre) k_xw<<<8192, 256, 0, stream>>>(X, Wx, bias, XW);
  for (int t = 0; t < Tn; t++) {
    if (pre)
      k_phase1<1><<<1024, 256, 0, stream>>>(h_cur, X, Wh, Wx, bias, alpha, XW,
                                            v_buf, t);
    else
      k_phase1<0><<<1024, 256, 0, stream>>>(h_cur, X, Wh, Wx, bias, alpha, XW,
                                            v_buf, t);
    k_phase2<<<1024, 256, 0, stream>>>(h_cur, v_buf, WhT, alpha, fc_w, out,
                                       hfin, t, t == Tn - 1);
  }
}